// Round 13
// baseline (280.660 us; speedup 1.0000x reference)
//
#include <hip/hip_runtime.h>
#include <hip/hip_bf16.h>
#include <hip/hip_cooperative_groups.h>

namespace cg = cooperative_groups;

#define LENGTH 4000
#define NPAD   4096
#define NB     8
#define CH     64
#define NP     4
#define NT2    32               // n-cols per mix chunk
#define BSTR   72               // sBt row stride (ushorts) = 9*16B: aligned b128 rows

using ushort8 = __attribute__((ext_vector_type(8))) unsigned short;
using short8v = __attribute__((ext_vector_type(8))) short;
using f32x4   = __attribute__((ext_vector_type(4))) float;

__device__ __forceinline__ unsigned short f2bu(float f) {
    __hip_bfloat16 h = __float2bfloat16(f);
    return __builtin_bit_cast(unsigned short, h);
}
__device__ __forceinline__ float bu2f(unsigned short u) {
    __hip_bfloat16 h = __builtin_bit_cast(__hip_bfloat16, u);
    return __bfloat162float(h);
}

// 8-point unnormalized Sylvester FWHT in registers.
__device__ __forceinline__ void fwht8(float v[8]) {
    #pragma unroll
    for (int h = 1; h < 8; h <<= 1)
        #pragma unroll
        for (int j = 0; j < 8; j += 2 * h)
            #pragma unroll
            for (int k = j; k < j + h; ++k) {
                float a = v[k], b = v[k + h];
                v[k] = a + b; v[k + h] = a - b;
            }
}

// Padded LDS address: every 8-float group padded by 1.
#define LADR(n) ((((n) >> 3) * 9) + ((n) & 7))
#define LDSZ 4608   // 4096/8*9

// ============================ fused cooperative kernel ========================
// G = grid size (512: 1 row/block, 2 chunks/block; 256: 2 rows, 4 chunks).
template<int G>
__global__ __launch_bounds__(512, 3) void k_fused(
        const float* __restrict__ x,
        unsigned short* __restrict__ f1b,
        const float* __restrict__ W,
        unsigned short* __restrict__ Wb,
        const float* __restrict__ T,
        const float* __restrict__ v,
        unsigned short* __restrict__ f6b,
        float* __restrict__ out) {
    __shared__ union {
        struct { float A[LDSZ]; float B[LDSZ]; } fw;     // 36.9 KB
        unsigned short mix[2][NT2 * BSTR];               // 9.2 KB
    } sh;
    cg::grid_group grid = cg::this_grid();
    const int bid = blockIdx.x;
    const int t = threadIdx.x;             // 0..511
    constexpr int RPB = 512 / G;           // rows per block in FWHT phases

    // ================= phase 1: forward FWHT (radix 8^4) ====================
    #pragma unroll
    for (int r = 0; r < RPB; ++r) {
        if (r) __syncthreads();
        const int row = bid + r * G;       // b*64 + i

        if (row < NP * CH && t < CH)       // W[po][i] -> bf16 copy (once)
            Wb[row * CH + t] = f2bu(W[row * CH + t]);

        float r8[8];
        if (t < 500) {                     // 500*8 == 4000
            const float* xr = x + (size_t)row * LENGTH + t * 8;
            float4 a = *(const float4*)xr, b = *(const float4*)(xr + 4);
            r8[0]=a.x; r8[1]=a.y; r8[2]=a.z; r8[3]=a.w;
            r8[4]=b.x; r8[5]=b.y; r8[6]=b.z; r8[7]=b.w;
        } else {
            #pragma unroll
            for (int j = 0; j < 8; ++j) r8[j] = 0.f;
        }
        fwht8(r8);                         // d0

        #pragma unroll
        for (int j = 0; j < 8; ++j) sh.fw.A[LADR(t * 8 + j)] = r8[j];
        __syncthreads();
        const int s1 = (t >> 3) * 64 + (t & 7);
        #pragma unroll
        for (int j = 0; j < 8; ++j) r8[j] = sh.fw.A[LADR(s1 + j * 8)];
        fwht8(r8);                         // d1

        #pragma unroll
        for (int j = 0; j < 8; ++j) sh.fw.B[LADR(s1 + j * 8)] = r8[j];
        __syncthreads();
        const int s2 = (t >> 6) * 512 + ((t >> 3) & 7) * 8 + (t & 7);
        #pragma unroll
        for (int j = 0; j < 8; ++j) r8[j] = sh.fw.B[LADR(s2 + j * 64)];
        fwht8(r8);                         // d2

        #pragma unroll
        for (int j = 0; j < 8; ++j) sh.fw.A[LADR(s2 + j * 64)] = r8[j];
        __syncthreads();
        #pragma unroll
        for (int j = 0; j < 8; ++j) r8[j] = sh.fw.A[LADR(j * 512 + t)];
        fwht8(r8);                         // d3

        unsigned short* fr = f1b + (size_t)row * NPAD;
        #pragma unroll
        for (int j = 0; j < 8; ++j)
            fr[j * 512 + t] = f2bu(r8[j]);
    }

    __threadfence();
    grid.sync();

    // ================= phase 2: MFMA mix ====================================
    {
        const int half = t >> 8;           // waves 0-3 -> half 0, 4-7 -> half 1
        const int t8 = t & 255;
        constexpr int BPB = G / NB;        // blocks per batch
        constexpr int CPB = 128 / BPB;     // chunks per block (both halves)
        const int b = bid / BPB;
        const int base = (bid % BPB) * CPB;
        unsigned short* sBt = sh.mix[half];
        const int lane = t8 & 63;
        const int w = t8 >> 6;             // wave-in-half 0..3
        const int l15 = lane & 15, lq = lane >> 4;

        short8v afrag[NP][2];              // same for all chunks
        #pragma unroll
        for (int p = 0; p < NP; ++p)
            #pragma unroll
            for (int ks = 0; ks < 2; ++ks)
                afrag[p][ks] = *(const short8v*)(Wb +
                    (size_t)(p * 64 + w * 16 + l15) * CH + ks * 32 + lq * 8);

        #pragma unroll
        for (int it = 0; it < CPB / 2; ++it) {
            const int nchunk = base + it * 2 + half;
            const int nbase = nchunk * NT2;

            {   // stage f1 tile 64i x 32n -> sBt[n][i]
                const int i = t8 >> 2, n0 = (t8 & 3) * 8;
                const unsigned short* src =
                    f1b + (size_t)(b * CH + i) * NPAD + nbase + n0;
                ushort8 rr = *(const ushort8*)src;
                #pragma unroll
                for (int j = 0; j < 8; ++j)
                    sBt[(n0 + j) * BSTR + i] = rr[j];
            }
            __syncthreads();

            short8v bfrag[2][2];
            #pragma unroll
            for (int nt = 0; nt < 2; ++nt)
                #pragma unroll
                for (int ks = 0; ks < 2; ++ks)
                    bfrag[nt][ks] = *(const short8v*)(
                        &sBt[(nt * 16 + l15) * BSTR + ks * 32 + lq * 8]);

            f32x4 acc[NP][2];
            #pragma unroll
            for (int p = 0; p < NP; ++p)
                #pragma unroll
                for (int nt = 0; nt < 2; ++nt) {
                    acc[p][nt] = (f32x4){0.f, 0.f, 0.f, 0.f};
                    #pragma unroll
                    for (int ks = 0; ks < 2; ++ks)
                        acc[p][nt] = __builtin_amdgcn_mfma_f32_16x16x32_bf16(
                            afrag[p][ks], bfrag[nt][ks], acc[p][nt], 0, 0, 0);
                }

            // epilogue: v*, soft-threshold, sum over p; C layout col=lane&15,
            // row=(lane>>4)*4+reg  [learn_hip m89]
            #pragma unroll
            for (int nt = 0; nt < 2; ++nt) {
                const int n = nbase + nt * 16 + l15;
                float outv[4] = {0.f, 0.f, 0.f, 0.f};
                #pragma unroll
                for (int p = 0; p < NP; ++p) {
                    const float vp = v[(size_t)p * NPAD + n];
                    const float tp = fabsf(T[(size_t)p * NPAD + n]);
                    #pragma unroll
                    for (int rr = 0; rr < 4; ++rr) {
                        float c = vp * acc[p][nt][rr];
                        float a = fabsf(c) - tp;
                        outv[rr] += (a > 0.f) ? copysignf(a, c) : 0.f;
                    }
                }
                #pragma unroll
                for (int rr = 0; rr < 4; ++rr) {
                    const int o = w * 16 + lq * 4 + rr;
                    f6b[(size_t)(b * CH + o) * NPAD + n] = f2bu(outv[rr]);
                }
            }
            __syncthreads();               // guard sBt reuse by next chunk
        }
    }

    __threadfence();
    grid.sync();

    // ================= phase 3: inverse FWHT, scale, trunc, +x ==============
    #pragma unroll
    for (int r = 0; r < RPB; ++r) {
        if (r) __syncthreads();
        const int row = bid + r * G;       // b*64 + o

        float r8[8];
        {
            const unsigned short* fr = f6b + (size_t)row * NPAD + t * 8;
            ushort8 rr = *(const ushort8*)fr;
            #pragma unroll
            for (int j = 0; j < 8; ++j) r8[j] = bu2f(rr[j]);
        }
        fwht8(r8);                         // d0

        #pragma unroll
        for (int j = 0; j < 8; ++j) sh.fw.A[LADR(t * 8 + j)] = r8[j];
        __syncthreads();
        const int s1 = (t >> 3) * 64 + (t & 7);
        #pragma unroll
        for (int j = 0; j < 8; ++j) r8[j] = sh.fw.A[LADR(s1 + j * 8)];
        fwht8(r8);                         // d1

        #pragma unroll
        for (int j = 0; j < 8; ++j) sh.fw.B[LADR(s1 + j * 8)] = r8[j];
        __syncthreads();
        const int s2 = (t >> 6) * 512 + ((t >> 3) & 7) * 8 + (t & 7);
        #pragma unroll
        for (int j = 0; j < 8; ++j) r8[j] = sh.fw.B[LADR(s2 + j * 64)];
        fwht8(r8);                         // d2

        #pragma unroll
        for (int j = 0; j < 8; ++j) sh.fw.A[LADR(s2 + j * 64)] = r8[j];
        __syncthreads();
        #pragma unroll
        for (int j = 0; j < 8; ++j) r8[j] = sh.fw.A[LADR(j * 512 + t)];
        fwht8(r8);                         // d3

        const float scale = 1.f / NPAD;
        const float* xr = x + (size_t)row * LENGTH;
        float* orow = out + (size_t)row * LENGTH;
        #pragma unroll
        for (int j = 0; j < 8; ++j) {
            const int n = j * 512 + t;
            if (n < LENGTH) orow[n] = r8[j] * scale + xr[n];
        }
    }
}

// ===================== fallback 3-kernel path (R10, proven) ===================
__global__ __launch_bounds__(512) void k_fwht_fwd(const float* __restrict__ x,
                                                  unsigned short* __restrict__ f1b,
                                                  const float* __restrict__ W,
                                                  unsigned short* __restrict__ Wb) {
    __shared__ float ldsA[LDSZ];
    __shared__ float ldsB[LDSZ];
    const int row = blockIdx.x;
    const int t = threadIdx.x;

    if (row < NP * CH && t < CH)
        Wb[row * CH + t] = f2bu(W[row * CH + t]);

    float v[8];
    if (t < 500) {
        const float* xr = x + (size_t)row * LENGTH + t * 8;
        float4 a = *(const float4*)xr, b = *(const float4*)(xr + 4);
        v[0]=a.x; v[1]=a.y; v[2]=a.z; v[3]=a.w;
        v[4]=b.x; v[5]=b.y; v[6]=b.z; v[7]=b.w;
    } else {
        #pragma unroll
        for (int j = 0; j < 8; ++j) v[j] = 0.f;
    }
    fwht8(v);

    #pragma unroll
    for (int j = 0; j < 8; ++j) ldsA[LADR(t * 8 + j)] = v[j];
    __syncthreads();
    const int s1 = (t >> 3) * 64 + (t & 7);
    #pragma unroll
    for (int j = 0; j < 8; ++j) v[j] = ldsA[LADR(s1 + j * 8)];
    fwht8(v);

    #pragma unroll
    for (int j = 0; j < 8; ++j) ldsB[LADR(s1 + j * 8)] = v[j];
    __syncthreads();
    const int s2 = (t >> 6) * 512 + ((t >> 3) & 7) * 8 + (t & 7);
    #pragma unroll
    for (int j = 0; j < 8; ++j) v[j] = ldsB[LADR(s2 + j * 64)];
    fwht8(v);

    #pragma unroll
    for (int j = 0; j < 8; ++j) ldsA[LADR(s2 + j * 64)] = v[j];
    __syncthreads();
    #pragma unroll
    for (int j = 0; j < 8; ++j) v[j] = ldsA[LADR(j * 512 + t)];
    fwht8(v);

    unsigned short* fr = f1b + (size_t)row * NPAD;
    #pragma unroll
    for (int j = 0; j < 8; ++j)
        fr[j * 512 + t] = f2bu(v[j]);
}

__global__ __launch_bounds__(256) void k_mix(const unsigned short* __restrict__ f1b,
                                             const unsigned short* __restrict__ Wb,
                                             const float* __restrict__ T,
                                             const float* __restrict__ v,
                                             unsigned short* __restrict__ f6b) {
    __shared__ unsigned short sBt[NT2 * BSTR];
    const int bid = blockIdx.x;
    const int nchunk = bid & 127;
    const int b = bid >> 7;
    const int nbase = nchunk * NT2;
    const int t = threadIdx.x;
    const int lane = t & 63;
    const int w = t >> 6;
    const int l15 = lane & 15, lq = lane >> 4;

    {
        const int i = t >> 2, n0 = (t & 3) * 8;
        const unsigned short* src =
            f1b + (size_t)(b * CH + i) * NPAD + nbase + n0;
        ushort8 r = *(const ushort8*)src;
        #pragma unroll
        for (int j = 0; j < 8; ++j)
            sBt[(n0 + j) * BSTR + i] = r[j];
    }

    short8v afrag[NP][2];
    #pragma unroll
    for (int p = 0; p < NP; ++p)
        #pragma unroll
        for (int ks = 0; ks < 2; ++ks)
            afrag[p][ks] = *(const short8v*)(Wb +
                (size_t)(p * 64 + w * 16 + l15) * CH + ks * 32 + lq * 8);

    __syncthreads();

    short8v bfrag[2][2];
    #pragma unroll
    for (int nt = 0; nt < 2; ++nt)
        #pragma unroll
        for (int ks = 0; ks < 2; ++ks)
            bfrag[nt][ks] = *(const short8v*)(
                &sBt[(nt * 16 + l15) * BSTR + ks * 32 + lq * 8]);

    f32x4 acc[NP][2];
    #pragma unroll
    for (int p = 0; p < NP; ++p)
        #pragma unroll
        for (int nt = 0; nt < 2; ++nt) {
            acc[p][nt] = (f32x4){0.f, 0.f, 0.f, 0.f};
            #pragma unroll
            for (int ks = 0; ks < 2; ++ks)
                acc[p][nt] = __builtin_amdgcn_mfma_f32_16x16x32_bf16(
                    afrag[p][ks], bfrag[nt][ks], acc[p][nt], 0, 0, 0);
        }

    #pragma unroll
    for (int nt = 0; nt < 2; ++nt) {
        const int n = nbase + nt * 16 + l15;
        float outv[4] = {0.f, 0.f, 0.f, 0.f};
        #pragma unroll
        for (int p = 0; p < NP; ++p) {
            const float vp = v[(size_t)p * NPAD + n];
            const float tp = fabsf(T[(size_t)p * NPAD + n]);
            #pragma unroll
            for (int r = 0; r < 4; ++r) {
                float c = vp * acc[p][nt][r];
                float a = fabsf(c) - tp;
                outv[r] += (a > 0.f) ? copysignf(a, c) : 0.f;
            }
        }
        #pragma unroll
        for (int r = 0; r < 4; ++r) {
            const int o = w * 16 + lq * 4 + r;
            f6b[(size_t)(b * CH + o) * NPAD + n] = f2bu(outv[r]);
        }
    }
}

__global__ __launch_bounds__(512) void k_fwht_inv(const unsigned short* __restrict__ f6b,
                                                  const float* __restrict__ x,
                                                  float* __restrict__ out) {
    __shared__ float ldsA[LDSZ];
    __shared__ float ldsB[LDSZ];
    const int row = blockIdx.x;
    const int t = threadIdx.x;

    float v[8];
    {
        const unsigned short* fr = f6b + (size_t)row * NPAD + t * 8;
        ushort8 r = *(const ushort8*)fr;
        #pragma unroll
        for (int j = 0; j < 8; ++j) v[j] = bu2f(r[j]);
    }
    fwht8(v);

    #pragma unroll
    for (int j = 0; j < 8; ++j) ldsA[LADR(t * 8 + j)] = v[j];
    __syncthreads();
    const int s1 = (t >> 3) * 64 + (t & 7);
    #pragma unroll
    for (int j = 0; j < 8; ++j) v[j] = ldsA[LADR(s1 + j * 8)];
    fwht8(v);

    #pragma unroll
    for (int j = 0; j < 8; ++j) ldsB[LADR(s1 + j * 8)] = v[j];
    __syncthreads();
    const int s2 = (t >> 6) * 512 + ((t >> 3) & 7) * 8 + (t & 7);
    #pragma unroll
    for (int j = 0; j < 8; ++j) v[j] = ldsB[LADR(s2 + j * 64)];
    fwht8(v);

    #pragma unroll
    for (int j = 0; j < 8; ++j) ldsA[LADR(s2 + j * 64)] = v[j];
    __syncthreads();
    #pragma unroll
    for (int j = 0; j < 8; ++j) v[j] = ldsA[LADR(j * 512 + t)];
    fwht8(v);

    const float scale = 1.f / NPAD;
    const float* xr = x + (size_t)row * LENGTH;
    float* orow = out + (size_t)row * LENGTH;
    #pragma unroll
    for (int j = 0; j < 8; ++j) {
        const int n = j * 512 + t;
        if (n < LENGTH) orow[n] = v[j] * scale + xr[n];
    }
}

extern "C" void kernel_launch(void* const* d_in, const int* in_sizes, int n_in,
                              void* d_out, int out_size, void* d_ws, size_t ws_size,
                              hipStream_t stream) {
    (void)in_sizes; (void)n_in; (void)out_size; (void)ws_size;
    const float* x = (const float*)d_in[0];
    const float* W = (const float*)d_in[1];
    const float* T = (const float*)d_in[2];
    const float* v = (const float*)d_in[3];
    float* out = (float*)d_out;
    unsigned short* f1b = (unsigned short*)d_ws;                 // 4 MB
    unsigned short* f6b = f1b + (size_t)NB * CH * NPAD;          // 4 MB
    unsigned short* Wb  = f6b + (size_t)NB * CH * NPAD;          // 32 KB

    void* args[] = {(void*)&x, (void*)&f1b, (void*)&W, (void*)&Wb,
                    (void*)&T, (void*)&v, (void*)&f6b, (void*)&out};

    // Cascade: coop G=512 (2 blocks/CU) -> coop G=256 (1 block/CU) -> 3-kernel.
    hipError_t e = hipLaunchCooperativeKernel((void*)k_fused<512>, dim3(512),
                                              dim3(512), args, 0, stream);
    if (e != hipSuccess)
        e = hipLaunchCooperativeKernel((void*)k_fused<256>, dim3(256),
                                       dim3(512), args, 0, stream);
    if (e != hipSuccess) {
        k_fwht_fwd<<<NB * CH, 512, 0, stream>>>(x, f1b, W, Wb);
        k_mix<<<NB * (NPAD / NT2), 256, 0, stream>>>(f1b, Wb, T, v, f6b);
        k_fwht_inv<<<NB * CH, 512, 0, stream>>>(f6b, x, out);
    }
}

// Round 14
// 23.096 us; speedup vs baseline: 12.1520x; 12.1520x over previous
//
#include <hip/hip_runtime.h>
#include <hip/hip_bf16.h>

#define LENGTH 4000
#define NPAD   4096
#define NB     8
#define CH     64
#define NP     4
#define NT2    32               // n-cols per k_mix block
#define BSTR   72               // sBt row stride (ushorts) = 9*16B: aligned b128 rows

using ushort8 = __attribute__((ext_vector_type(8))) unsigned short;
using short8v = __attribute__((ext_vector_type(8))) short;
using f32x4   = __attribute__((ext_vector_type(4))) float;

__device__ __forceinline__ unsigned short f2bu(float f) {
    __hip_bfloat16 h = __float2bfloat16(f);
    return __builtin_bit_cast(unsigned short, h);
}
__device__ __forceinline__ float bu2f(unsigned short u) {
    __hip_bfloat16 h = __builtin_bit_cast(__hip_bfloat16, u);
    return __bfloat162float(h);
}

// 8-point unnormalized Sylvester FWHT in registers.
__device__ __forceinline__ void fwht8(float v[8]) {
    #pragma unroll
    for (int h = 1; h < 8; h <<= 1)
        #pragma unroll
        for (int j = 0; j < 8; j += 2 * h)
            #pragma unroll
            for (int k = j; k < j + h; ++k) {
                float a = v[k], b = v[k + h];
                v[k] = a + b; v[k + h] = a - b;
            }
}

// Padded LDS address: every 8-float group padded by 1 -> all digit-stride
// exchanges are <=3-way bank aliased.
#define LADR(n) ((((n) >> 3) * 9) + ((n) & 7))
#define LDSZ 4608   // 4096/8*9

// ---------------- K1: forward FWHT (radix 8^4, 512 thr) -> f1 bf16 ------------
__global__ __launch_bounds__(512) void k_fwht_fwd(const float* __restrict__ x,
                                                  unsigned short* __restrict__ f1b,
                                                  const float* __restrict__ W,
                                                  unsigned short* __restrict__ Wb) {
    __shared__ float ldsA[LDSZ];
    __shared__ float ldsB[LDSZ];
    const int row = blockIdx.x;            // b*64 + i
    const int t = threadIdx.x;

    if (row < NP * CH && t < CH)           // W[po][i] -> bf16 copy (once)
        Wb[row * CH + t] = f2bu(W[row * CH + t]);

    float v[8];
    if (t < 500) {                         // 500*8 == 4000
        const float* xr = x + (size_t)row * LENGTH + t * 8;
        float4 a = *(const float4*)xr, b = *(const float4*)(xr + 4);
        v[0]=a.x; v[1]=a.y; v[2]=a.z; v[3]=a.w;
        v[4]=b.x; v[5]=b.y; v[6]=b.z; v[7]=b.w;
    } else {
        #pragma unroll
        for (int j = 0; j < 8; ++j) v[j] = 0.f;
    }
    fwht8(v);                              // over d0

    #pragma unroll
    for (int j = 0; j < 8; ++j) ldsA[LADR(t * 8 + j)] = v[j];
    __syncthreads();
    const int s1 = (t >> 3) * 64 + (t & 7);
    #pragma unroll
    for (int j = 0; j < 8; ++j) v[j] = ldsA[LADR(s1 + j * 8)];
    fwht8(v);                              // over d1

    #pragma unroll
    for (int j = 0; j < 8; ++j) ldsB[LADR(s1 + j * 8)] = v[j];
    __syncthreads();
    const int s2 = (t >> 6) * 512 + ((t >> 3) & 7) * 8 + (t & 7);
    #pragma unroll
    for (int j = 0; j < 8; ++j) v[j] = ldsB[LADR(s2 + j * 64)];
    fwht8(v);                              // over d2

    #pragma unroll
    for (int j = 0; j < 8; ++j) ldsA[LADR(s2 + j * 64)] = v[j];
    __syncthreads();
    #pragma unroll
    for (int j = 0; j < 8; ++j) v[j] = ldsA[LADR(j * 512 + t)];
    fwht8(v);                              // over d3

    unsigned short* fr = f1b + (size_t)row * NPAD;
    #pragma unroll
    for (int j = 0; j < 8; ++j)
        fr[j * 512 + t] = f2bu(v[j]);
}

// ---------------- K2: MFMA channel mix (proven R9/R10 structure) --------------
__global__ __launch_bounds__(256) void k_mix(const unsigned short* __restrict__ f1b,
                                             const unsigned short* __restrict__ Wb,
                                             const float* __restrict__ T,
                                             const float* __restrict__ v,
                                             unsigned short* __restrict__ f6b) {
    __shared__ unsigned short sBt[NT2 * BSTR];   // [n][i] transposed, 4.6 KB
    const int bid = blockIdx.x;            // b*128 + nchunk
    const int nchunk = bid & 127;
    const int b = bid >> 7;
    const int nbase = nchunk * NT2;
    const int t = threadIdx.x;
    const int lane = t & 63;
    const int w = t >> 6;                  // wave id 0..3
    const int l15 = lane & 15, lq = lane >> 4;

    {
        const int i = t >> 2, n0 = (t & 3) * 8;
        const unsigned short* src =
            f1b + (size_t)(b * CH + i) * NPAD + nbase + n0;
        ushort8 r = *(const ushort8*)src;
        #pragma unroll
        for (int j = 0; j < 8; ++j)
            sBt[(n0 + j) * BSTR + i] = r[j];
    }

    short8v afrag[NP][2];
    #pragma unroll
    for (int p = 0; p < NP; ++p)
        #pragma unroll
        for (int ks = 0; ks < 2; ++ks)
            afrag[p][ks] = *(const short8v*)(Wb +
                (size_t)(p * 64 + w * 16 + l15) * CH + ks * 32 + lq * 8);

    __syncthreads();

    short8v bfrag[2][2];
    #pragma unroll
    for (int nt = 0; nt < 2; ++nt)
        #pragma unroll
        for (int ks = 0; ks < 2; ++ks)
            bfrag[nt][ks] = *(const short8v*)(
                &sBt[(nt * 16 + l15) * BSTR + ks * 32 + lq * 8]);

    f32x4 acc[NP][2];
    #pragma unroll
    for (int p = 0; p < NP; ++p)
        #pragma unroll
        for (int nt = 0; nt < 2; ++nt) {
            acc[p][nt] = (f32x4){0.f, 0.f, 0.f, 0.f};
            #pragma unroll
            for (int ks = 0; ks < 2; ++ks)
                acc[p][nt] = __builtin_amdgcn_mfma_f32_16x16x32_bf16(
                    afrag[p][ks], bfrag[nt][ks], acc[p][nt], 0, 0, 0);
        }

    // epilogue: v*, soft-threshold, sum over p; C layout col=lane&15,
    // row=(lane>>4)*4+reg  [learn_hip m89]
    #pragma unroll
    for (int nt = 0; nt < 2; ++nt) {
        const int n = nbase + nt * 16 + l15;
        float outv[4] = {0.f, 0.f, 0.f, 0.f};
        #pragma unroll
        for (int p = 0; p < NP; ++p) {
            const float vp = v[(size_t)p * NPAD + n];
            const float tp = fabsf(T[(size_t)p * NPAD + n]);
            #pragma unroll
            for (int r = 0; r < 4; ++r) {
                float c = vp * acc[p][nt][r];
                float a = fabsf(c) - tp;
                outv[r] += (a > 0.f) ? copysignf(a, c) : 0.f;
            }
        }
        #pragma unroll
        for (int r = 0; r < 4; ++r) {
            const int o = w * 16 + lq * 4 + r;
            f6b[(size_t)(b * CH + o) * NPAD + n] = f2bu(outv[r]);
        }
    }
}

// ---------------- K3: inverse FWHT (radix 8^4), scale, trunc, +x --------------
__global__ __launch_bounds__(512) void k_fwht_inv(const unsigned short* __restrict__ f6b,
                                                  const float* __restrict__ x,
                                                  float* __restrict__ out) {
    __shared__ float ldsA[LDSZ];
    __shared__ float ldsB[LDSZ];
    const int row = blockIdx.x;            // b*64 + o
    const int t = threadIdx.x;

    float v[8];
    {
        const unsigned short* fr = f6b + (size_t)row * NPAD + t * 8;
        ushort8 r = *(const ushort8*)fr;
        #pragma unroll
        for (int j = 0; j < 8; ++j) v[j] = bu2f(r[j]);
    }
    fwht8(v);                              // d0

    #pragma unroll
    for (int j = 0; j < 8; ++j) ldsA[LADR(t * 8 + j)] = v[j];
    __syncthreads();
    const int s1 = (t >> 3) * 64 + (t & 7);
    #pragma unroll
    for (int j = 0; j < 8; ++j) v[j] = ldsA[LADR(s1 + j * 8)];
    fwht8(v);                              // d1

    #pragma unroll
    for (int j = 0; j < 8; ++j) ldsB[LADR(s1 + j * 8)] = v[j];
    __syncthreads();
    const int s2 = (t >> 6) * 512 + ((t >> 3) & 7) * 8 + (t & 7);
    #pragma unroll
    for (int j = 0; j < 8; ++j) v[j] = ldsB[LADR(s2 + j * 64)];
    fwht8(v);                              // d2

    #pragma unroll
    for (int j = 0; j < 8; ++j) ldsA[LADR(s2 + j * 64)] = v[j];
    __syncthreads();
    #pragma unroll
    for (int j = 0; j < 8; ++j) v[j] = ldsA[LADR(j * 512 + t)];
    fwht8(v);                              // d3

    const float scale = 1.f / NPAD;
    const float* xr = x + (size_t)row * LENGTH;
    float* orow = out + (size_t)row * LENGTH;
    #pragma unroll
    for (int j = 0; j < 8; ++j) {
        const int n = j * 512 + t;
        if (n < LENGTH) orow[n] = v[j] * scale + xr[n];
    }
}

extern "C" void kernel_launch(void* const* d_in, const int* in_sizes, int n_in,
                              void* d_out, int out_size, void* d_ws, size_t ws_size,
                              hipStream_t stream) {
    (void)in_sizes; (void)n_in; (void)out_size; (void)ws_size;
    const float* x = (const float*)d_in[0];
    const float* W = (const float*)d_in[1];
    const float* T = (const float*)d_in[2];
    const float* v = (const float*)d_in[3];
    float* out = (float*)d_out;
    unsigned short* f1b = (unsigned short*)d_ws;                 // 4 MB
    unsigned short* f6b = f1b + (size_t)NB * CH * NPAD;          // 4 MB
    unsigned short* Wb  = f6b + (size_t)NB * CH * NPAD;          // 32 KB

    k_fwht_fwd<<<NB * CH, 512, 0, stream>>>(x, f1b, W, Wb);
    k_mix<<<NB * (NPAD / NT2), 256, 0, stream>>>(f1b, Wb, T, v, f6b);
    k_fwht_inv<<<NB * CH, 512, 0, stream>>>(f6b, x, out);
}

// Round 15
// 22.872 us; speedup vs baseline: 12.2710x; 1.0098x over previous
//
#include <hip/hip_runtime.h>
#include <hip/hip_bf16.h>

#define LENGTH 4000
#define NPAD   4096
#define NB     8
#define CH     64
#define NP     4
#define NT2    32               // n-cols per k_mix block
#define BSTR   72               // sBt row stride (ushorts) = 9*16B: aligned b128 rows

using ushort8 = __attribute__((ext_vector_type(8))) unsigned short;
using short8v = __attribute__((ext_vector_type(8))) short;
using f32x4   = __attribute__((ext_vector_type(4))) float;

__device__ __forceinline__ unsigned short f2bu(float f) {
    __hip_bfloat16 h = __float2bfloat16(f);
    return __builtin_bit_cast(unsigned short, h);
}
__device__ __forceinline__ float bu2f(unsigned short u) {
    __hip_bfloat16 h = __builtin_bit_cast(__hip_bfloat16, u);
    return __bfloat162float(h);
}

// 8-point unnormalized Sylvester FWHT in registers.
__device__ __forceinline__ void fwht8(float v[8]) {
    #pragma unroll
    for (int h = 1; h < 8; h <<= 1)
        #pragma unroll
        for (int j = 0; j < 8; j += 2 * h)
            #pragma unroll
            for (int k = j; k < j + h; ++k) {
                float a = v[k], b = v[k + h];
                v[k] = a + b; v[k + h] = a - b;
            }
}

// Padded LDS address: every 8-float group padded by 1 -> all digit-stride
// exchanges are <=3-way bank aliased.
#define LADR(n) ((((n) >> 3) * 9) + ((n) & 7))
#define LDSZ 4608   // 4096/8*9

// f1 is stored CHUNK-TILED for k_mix: f1t[b][chunk(128)][i(64)][nl(32)].
// k_mix (sole consumer) then stages one contiguous 4KB block instead of 64
// stride-4096 segments.

// ---------------- K1: forward FWHT (radix 8^4, 512 thr) -> f1t bf16 -----------
__global__ __launch_bounds__(512) void k_fwht_fwd(const float* __restrict__ x,
                                                  unsigned short* __restrict__ f1t,
                                                  const float* __restrict__ W,
                                                  unsigned short* __restrict__ Wb) {
    __shared__ float ldsA[LDSZ];
    __shared__ float ldsB[LDSZ];
    const int row = blockIdx.x;            // b*64 + i
    const int t = threadIdx.x;

    if (row < NP * CH && t < CH)           // W[po][i] -> bf16 copy (once)
        Wb[row * CH + t] = f2bu(W[row * CH + t]);

    float v[8];
    if (t < 500) {                         // 500*8 == 4000
        const float* xr = x + (size_t)row * LENGTH + t * 8;
        float4 a = *(const float4*)xr, b = *(const float4*)(xr + 4);
        v[0]=a.x; v[1]=a.y; v[2]=a.z; v[3]=a.w;
        v[4]=b.x; v[5]=b.y; v[6]=b.z; v[7]=b.w;
    } else {
        #pragma unroll
        for (int j = 0; j < 8; ++j) v[j] = 0.f;
    }
    fwht8(v);                              // over d0

    #pragma unroll
    for (int j = 0; j < 8; ++j) ldsA[LADR(t * 8 + j)] = v[j];
    __syncthreads();
    const int s1 = (t >> 3) * 64 + (t & 7);
    #pragma unroll
    for (int j = 0; j < 8; ++j) v[j] = ldsA[LADR(s1 + j * 8)];
    fwht8(v);                              // over d1

    #pragma unroll
    for (int j = 0; j < 8; ++j) ldsB[LADR(s1 + j * 8)] = v[j];
    __syncthreads();
    const int s2 = (t >> 6) * 512 + ((t >> 3) & 7) * 8 + (t & 7);
    #pragma unroll
    for (int j = 0; j < 8; ++j) v[j] = ldsB[LADR(s2 + j * 64)];
    fwht8(v);                              // over d2

    #pragma unroll
    for (int j = 0; j < 8; ++j) ldsA[LADR(s2 + j * 64)] = v[j];
    __syncthreads();
    #pragma unroll
    for (int j = 0; j < 8; ++j) v[j] = ldsA[LADR(j * 512 + t)];
    fwht8(v);                              // over d3

    // tiled store: n = j*512+t -> [b][n>>5][i][n&31]
    const int b = row >> 6, i = row & 63;
    unsigned short* fb = f1t + ((size_t)b * 128 * 64 + (size_t)i) * 32;
    #pragma unroll
    for (int j = 0; j < 8; ++j) {
        const int n = j * 512 + t;
        fb[(size_t)(n >> 5) * (64 * 32) + (n & 31)] = f2bu(v[j]);
    }
}

// ---------------- K2: MFMA channel mix (tiled staging + hoisted v/T) ----------
__global__ __launch_bounds__(256) void k_mix(const unsigned short* __restrict__ f1t,
                                             const unsigned short* __restrict__ Wb,
                                             const float* __restrict__ T,
                                             const float* __restrict__ v,
                                             unsigned short* __restrict__ f6b) {
    __shared__ unsigned short sBt[NT2 * BSTR];   // [n][i] transposed, 4.6 KB
    const int bid = blockIdx.x;            // b*128 + nchunk
    const int nchunk = bid & 127;
    const int b = bid >> 7;
    const int nbase = nchunk * NT2;
    const int t = threadIdx.x;
    const int lane = t & 63;
    const int w = t >> 6;                  // wave id 0..3
    const int l15 = lane & 15, lq = lane >> 4;

    {   // stage tile: ONE contiguous 4KB block (tiled [i][nl] layout)
        const unsigned short* src =
            f1t + (size_t)(b * 128 + nchunk) * (64 * 32) + t * 8;
        ushort8 r = *(const ushort8*)src;
        const int i = t >> 2, n0 = (t & 3) * 8;
        #pragma unroll
        for (int j = 0; j < 8; ++j)
            sBt[(n0 + j) * BSTR + i] = r[j];
    }

    short8v afrag[NP][2];
    #pragma unroll
    for (int p = 0; p < NP; ++p)
        #pragma unroll
        for (int ks = 0; ks < 2; ++ks)
            afrag[p][ks] = *(const short8v*)(Wb +
                (size_t)(p * 64 + w * 16 + l15) * CH + ks * 32 + lq * 8);

    // hoist v/T loads: latency hides under barrier + MFMA phase
    float vp_[2][NP], tp_[2][NP];
    #pragma unroll
    for (int nt = 0; nt < 2; ++nt) {
        const int n = nbase + nt * 16 + l15;
        #pragma unroll
        for (int p = 0; p < NP; ++p) {
            vp_[nt][p] = v[(size_t)p * NPAD + n];
            tp_[nt][p] = fabsf(T[(size_t)p * NPAD + n]);
        }
    }

    __syncthreads();

    short8v bfrag[2][2];
    #pragma unroll
    for (int nt = 0; nt < 2; ++nt)
        #pragma unroll
        for (int ks = 0; ks < 2; ++ks)
            bfrag[nt][ks] = *(const short8v*)(
                &sBt[(nt * 16 + l15) * BSTR + ks * 32 + lq * 8]);

    f32x4 acc[NP][2];
    #pragma unroll
    for (int p = 0; p < NP; ++p)
        #pragma unroll
        for (int nt = 0; nt < 2; ++nt) {
            acc[p][nt] = (f32x4){0.f, 0.f, 0.f, 0.f};
            #pragma unroll
            for (int ks = 0; ks < 2; ++ks)
                acc[p][nt] = __builtin_amdgcn_mfma_f32_16x16x32_bf16(
                    afrag[p][ks], bfrag[nt][ks], acc[p][nt], 0, 0, 0);
        }

    // epilogue: v*, soft-threshold, sum over p; C layout col=lane&15,
    // row=(lane>>4)*4+reg  [learn_hip m89]
    #pragma unroll
    for (int nt = 0; nt < 2; ++nt) {
        const int n = nbase + nt * 16 + l15;
        float outv[4] = {0.f, 0.f, 0.f, 0.f};
        #pragma unroll
        for (int p = 0; p < NP; ++p) {
            #pragma unroll
            for (int r = 0; r < 4; ++r) {
                float c = vp_[nt][p] * acc[p][nt][r];
                float a = fabsf(c) - tp_[nt][p];
                outv[r] += (a > 0.f) ? copysignf(a, c) : 0.f;
            }
        }
        #pragma unroll
        for (int r = 0; r < 4; ++r) {
            const int o = w * 16 + lq * 4 + r;
            f6b[(size_t)(b * CH + o) * NPAD + n] = f2bu(outv[r]);
        }
    }
}

// ---------------- K3: inverse FWHT (radix 8^4), scale, trunc, +x --------------
__global__ __launch_bounds__(512) void k_fwht_inv(const unsigned short* __restrict__ f6b,
                                                  const float* __restrict__ x,
                                                  float* __restrict__ out) {
    __shared__ float ldsA[LDSZ];
    __shared__ float ldsB[LDSZ];
    const int row = blockIdx.x;            // b*64 + o
    const int t = threadIdx.x;

    float v[8];
    {
        const unsigned short* fr = f6b + (size_t)row * NPAD + t * 8;
        ushort8 r = *(const ushort8*)fr;
        #pragma unroll
        for (int j = 0; j < 8; ++j) v[j] = bu2f(r[j]);
    }
    fwht8(v);                              // d0

    #pragma unroll
    for (int j = 0; j < 8; ++j) ldsA[LADR(t * 8 + j)] = v[j];
    __syncthreads();
    const int s1 = (t >> 3) * 64 + (t & 7);
    #pragma unroll
    for (int j = 0; j < 8; ++j) v[j] = ldsA[LADR(s1 + j * 8)];
    fwht8(v);                              // d1

    #pragma unroll
    for (int j = 0; j < 8; ++j) ldsB[LADR(s1 + j * 8)] = v[j];
    __syncthreads();
    const int s2 = (t >> 6) * 512 + ((t >> 3) & 7) * 8 + (t & 7);
    #pragma unroll
    for (int j = 0; j < 8; ++j) v[j] = ldsB[LADR(s2 + j * 64)];
    fwht8(v);                              // d2

    #pragma unroll
    for (int j = 0; j < 8; ++j) ldsA[LADR(s2 + j * 64)] = v[j];
    __syncthreads();
    #pragma unroll
    for (int j = 0; j < 8; ++j) v[j] = ldsA[LADR(j * 512 + t)];
    fwht8(v);                              // d3

    const float scale = 1.f / NPAD;
    const float* xr = x + (size_t)row * LENGTH;
    float* orow = out + (size_t)row * LENGTH;
    #pragma unroll
    for (int j = 0; j < 8; ++j) {
        const int n = j * 512 + t;
        if (n < LENGTH) orow[n] = v[j] * scale + xr[n];
    }
}

extern "C" void kernel_launch(void* const* d_in, const int* in_sizes, int n_in,
                              void* d_out, int out_size, void* d_ws, size_t ws_size,
                              hipStream_t stream) {
    (void)in_sizes; (void)n_in; (void)out_size; (void)ws_size;
    const float* x = (const float*)d_in[0];
    const float* W = (const float*)d_in[1];
    const float* T = (const float*)d_in[2];
    const float* v = (const float*)d_in[3];
    float* out = (float*)d_out;
    unsigned short* f1t = (unsigned short*)d_ws;                 // 4 MB (tiled)
    unsigned short* f6b = f1t + (size_t)NB * CH * NPAD;          // 4 MB
    unsigned short* Wb  = f6b + (size_t)NB * CH * NPAD;          // 32 KB

    k_fwht_fwd<<<NB * CH, 512, 0, stream>>>(x, f1t, W, Wb);
    k_mix<<<NB * (NPAD / NT2), 256, 0, stream>>>(f1t, Wb, T, v, f6b);
    k_fwht_inv<<<NB * CH, 512, 0, stream>>>(f6b, x, out);
}